// Round 8
// baseline (278.846 us; speedup 1.0000x reference)
//
#include <hip/hip_runtime.h>
#include <cstdint>

#define EPSN 1e-12f
static constexpr int B_ROWS = 1024;
static constexpr int IN_DIM = 512;
static constexpr int OUT_DIM = 64000;

typedef __attribute__((ext_vector_type(8))) short bf16x8;
typedef __attribute__((ext_vector_type(4))) float f32x4;

__device__ __forceinline__ unsigned short f2bf(float f) {
  uint32_t u = __builtin_bit_cast(uint32_t, f);
  u += 0x7fffu + ((u >> 16) & 1u);   // round-to-nearest-even
  return (unsigned short)(u >> 16);
}

__device__ __forceinline__ float bf2f(unsigned short h) {
  uint32_t u = (uint32_t)h << 16;
  return __builtin_bit_cast(float, u);
}

__device__ __forceinline__ float wave_sum(float v) {
#pragma unroll
  for (int off = 32; off; off >>= 1) v += __shfl_xor(v, off);
  return v;
}

__device__ __forceinline__ void async16(const void* g, void* l) {
  __builtin_amdgcn_global_load_lds((const __attribute__((address_space(1))) uint32_t*)g,
                                   (__attribute__((address_space(3))) uint32_t*)l, 16, 0, 0);
}

// --- kernel 1: x-prep (norms + bf16 cast) + exact fixdot from RAW W ---
__global__ void prep_kernel(const float* __restrict__ X, const int* __restrict__ label,
                            const float* __restrict__ Wg, float* __restrict__ norms,
                            float* __restrict__ fixdot, unsigned short* __restrict__ xbf) {
  int lane = threadIdx.x & 63;
  int row = blockIdx.x * 4 + (threadIdx.x >> 6);
  const float* src = X + (size_t)row * IN_DIM + lane * 8;
  float4 a = *(const float4*)src;
  float4 b = *(const float4*)(src + 4);
  uint4 u;
  u.x = (uint32_t)f2bf(a.x) | ((uint32_t)f2bf(a.y) << 16);
  u.y = (uint32_t)f2bf(a.z) | ((uint32_t)f2bf(a.w) << 16);
  u.z = (uint32_t)f2bf(b.x) | ((uint32_t)f2bf(b.y) << 16);
  u.w = (uint32_t)f2bf(b.z) | ((uint32_t)f2bf(b.w) << 16);
  *(uint4*)(xbf + (size_t)row * IN_DIM + lane * 8) = u;
  float ssx = a.x * a.x;
  ssx = fmaf(a.y, a.y, ssx); ssx = fmaf(a.z, a.z, ssx); ssx = fmaf(a.w, a.w, ssx);
  ssx = fmaf(b.x, b.x, ssx); ssx = fmaf(b.y, b.y, ssx); ssx = fmaf(b.z, b.z, ssx);
  ssx = fmaf(b.w, b.w, ssx);
  int lab = label[row];
  const float* wsrc = Wg + (size_t)lab * IN_DIM + lane * 8;
  float4 wa = *(const float4*)wsrc, wb = *(const float4*)(wsrc + 4);
  float d = a.x * wa.x;
  d = fmaf(a.y, wa.y, d); d = fmaf(a.z, wa.z, d); d = fmaf(a.w, wa.w, d);
  d = fmaf(b.x, wb.x, d); d = fmaf(b.y, wb.y, d); d = fmaf(b.z, wb.z, d);
  d = fmaf(b.w, wb.w, d);
  float ssw = wa.x * wa.x;
  ssw = fmaf(wa.y, wa.y, ssw); ssw = fmaf(wa.z, wa.z, ssw); ssw = fmaf(wa.w, wa.w, ssw);
  ssw = fmaf(wb.x, wb.x, ssw); ssw = fmaf(wb.y, wb.y, ssw); ssw = fmaf(wb.z, wb.z, ssw);
  ssw = fmaf(wb.w, wb.w, ssw);
  ssx = wave_sum(ssx);
  d = wave_sum(d);
  ssw = wave_sum(ssw);
  if (lane == 0) {
    norms[row] = sqrtf(ssx);
    fixdot[row] = d / fmaxf(sqrtf(ssw), EPSN);   // = x . wn[lab], exact f32
  }
}

// --- kernel 2: FUSED normalize + GEMM + margin epilogue + wn write ---
// BM=256, BN=128. B panel [128][512] bf16 STATIC in LDS (131072 B, swizzled
// slot^=(r&7), both-sides), normalized at init from raw W f32 (L2-shared by the
// 4 mT siblings; init loads fully drained before K-loop -> no vmcnt pollution).
// A (xbf, L2-resident) via gload_lds ring-2 (2x16 KiB), counted vmcnt(2), two
// barriers/phase (reissue of slot sig&1 only after post-MFMA barrier).
// 8 waves (4Mx2N), wave-tile 64x64: acc[4][4], 16 MFMA/phase, 16 phases.
// Epilogue: wn f32 (32 rows, from resident LDS panel) + margin out writes.
__global__ __launch_bounds__(512, 2) void gemm_fused_kernel(
    const float* __restrict__ Wg, const unsigned short* __restrict__ Abf,
    const float* __restrict__ norms, const float* __restrict__ fixdot,
    const int* __restrict__ label, const float* __restrict__ mArr,
    float* __restrict__ out0, float* __restrict__ wnOut) {
  __shared__ char smem[163840];   // B @0 (128 KiB); A ring @131072 (2 x 16 KiB)

  const int t = threadIdx.x;
  int flat = blockIdx.x;          // 2000 = 8 * 250, bijective XCD swizzle
  int xcd = flat & 7;
  int wk = (flat >> 3) + xcd * 250;
  int mT = wk & 3, nT = wk >> 2;  // 4 mT siblings per nT consecutive on one XCD
  int rowA0 = mT * 256, rowB0 = nT * 128;

  int lane = t & 63;
  int wid = t >> 6;
  int wm = wid >> 1, wn2 = wid & 1;   // 4M x 2N wave grid
  int rl = lane & 15, sl = lane >> 4;

  // ---- init: normalize W panel into LDS bf16 (swizzled) ----
  // wave wid: rows wid*16..+16; per row all 64 lanes (8 floats each, coalesced)
#pragma unroll 1
  for (int rr = 0; rr < 16; ++rr) {
    int r = wid * 16 + rr;
    const float* src = Wg + (size_t)(rowB0 + r) * IN_DIM + lane * 8;
    float4 a = *(const float4*)src;
    float4 b = *(const float4*)(src + 4);
    float ss = a.x * a.x;
    ss = fmaf(a.y, a.y, ss); ss = fmaf(a.z, a.z, ss); ss = fmaf(a.w, a.w, ss);
    ss = fmaf(b.x, b.x, ss); ss = fmaf(b.y, b.y, ss); ss = fmaf(b.z, b.z, ss);
    ss = fmaf(b.w, b.w, ss);
    ss = wave_sum(ss);
    float inv = 1.0f / fmaxf(sqrtf(ss), EPSN);
    uint4 u;
    u.x = (uint32_t)f2bf(a.x * inv) | ((uint32_t)f2bf(a.y * inv) << 16);
    u.y = (uint32_t)f2bf(a.z * inv) | ((uint32_t)f2bf(a.w * inv) << 16);
    u.z = (uint32_t)f2bf(b.x * inv) | ((uint32_t)f2bf(b.y * inv) << 16);
    u.w = (uint32_t)f2bf(b.z * inv) | ((uint32_t)f2bf(b.w * inv) << 16);
    // logical slot = lane (16 B each, 64/row); stored at slot^(r&7)
    *(uint4*)(smem + r * 1024 + ((lane ^ (r & 7)) * 16)) = u;
  }
  __syncthreads();

  // ---- A staging (ring-2): inverse-swizzled global source, linear LDS dest ----
  int rA0 = t >> 2, qA0 = (t & 3) ^ ((rA0 >> 1) & 3);
  int rA1 = (t + 512) >> 2, qA1 = ((t + 512) & 3) ^ ((rA1 >> 1) & 3);
  const unsigned short* aP0 = Abf + (size_t)(rowA0 + rA0) * IN_DIM + qA0 * 8;
  const unsigned short* aP1 = Abf + (size_t)(rowA0 + rA1) * IN_DIM + qA1 * 8;

  auto issueA = [&](int sig) {
    char* aD = smem + 131072 + (sig & 1) * 16384;
    int kcol = sig * 32;
    async16(aP0 + kcol, aD + t * 16);
    async16(aP1 + kcol, aD + (t + 512) * 16);
  };

  issueA(0); issueA(1);   // depth-2 prologue (4 gloads outstanding)

  f32x4 acc[4][4];
#pragma unroll
  for (int m = 0; m < 4; ++m)
#pragma unroll
    for (int n = 0; n < 4; ++n) acc[m][n] = (f32x4){0.f, 0.f, 0.f, 0.f};

#pragma unroll 1
  for (int sigma = 0; sigma < 16; ++sigma) {
    __builtin_amdgcn_sched_barrier(0);
    if (sigma <= 14) asm volatile("s_waitcnt vmcnt(2)" ::: "memory");
    else             asm volatile("s_waitcnt vmcnt(0)" ::: "memory");
    __builtin_amdgcn_s_barrier();
    __builtin_amdgcn_sched_barrier(0);

    const char* aB = smem + 131072 + (sigma & 1) * 16384;
    bf16x8 av[4], bv[4];
#pragma unroll
    for (int m = 0; m < 4; ++m) {
      int r = wm * 64 + m * 16 + rl;
      av[m] = *(const bf16x8*)(aB + r * 64 + ((sl ^ ((r >> 1) & 3)) * 16));
    }
#pragma unroll
    for (int n = 0; n < 4; ++n) {
      int r = wn2 * 64 + n * 16 + rl;
      bv[n] = *(const bf16x8*)(smem + r * 1024 + (((sigma * 4 + sl) ^ (r & 7)) * 16));
    }
    __builtin_amdgcn_s_setprio(1);
#pragma unroll
    for (int n = 0; n < 4; ++n)
#pragma unroll
      for (int m = 0; m < 4; ++m)
        acc[m][n] = __builtin_amdgcn_mfma_f32_16x16x32_bf16(av[m], bv[n], acc[m][n], 0, 0, 0);
    __builtin_amdgcn_s_setprio(0);
    // all waves' reads of A slot (sigma&1) done before reissue into it:
    asm volatile("s_waitcnt lgkmcnt(0)" ::: "memory");
    __builtin_amdgcn_s_barrier();
    __builtin_amdgcn_sched_barrier(0);
    if (sigma + 2 <= 15) issueA(sigma + 2);
  }

  // ---- wn f32 output: this mT-sibling writes 32 rows from the resident LDS
  // panel (bf16-rounded; error << threshold). t: row t>>4, 32-col chunk t&15.
  {
    int r = mT * 32 + (t >> 4);          // panel-local row 0..127
    int row = rowB0 + r;
    float* dst = wnOut + (size_t)row * IN_DIM + (t & 15) * 32;
#pragma unroll
    for (int j = 0; j < 4; ++j) {
      int s = (t & 15) * 4 + j;          // logical 16B slot
      uint4 uu = *(const uint4*)(smem + r * 1024 + ((s ^ (r & 7)) * 16));
      float4 f;
      f.x = bf2f((unsigned short)(uu.x & 0xffff)); f.y = bf2f((unsigned short)(uu.x >> 16));
      f.z = bf2f((unsigned short)(uu.y & 0xffff)); f.w = bf2f((unsigned short)(uu.y >> 16));
      *(float4*)(dst + j * 8) = f;
      f.x = bf2f((unsigned short)(uu.z & 0xffff)); f.y = bf2f((unsigned short)(uu.z >> 16));
      f.z = bf2f((unsigned short)(uu.w & 0xffff)); f.w = bf2f((unsigned short)(uu.w >> 16));
      *(float4*)(dst + j * 8 + 4) = f;
    }
  }

  // ---- margin epilogue: out = rawdot except at (r, label[r]) ----
  float mm = mArr[0];
  float cm = cosf(mm), sm = sinf(mm);
  int rowb = rowA0 + wm * 64, colb = rowB0 + wn2 * 64;
#pragma unroll
  for (int m = 0; m < 4; ++m) {
#pragma unroll
    for (int q = 0; q < 4; ++q) {
      int R = rowb + m * 16 + sl * 4 + q;
      int lab = label[R];
      float nv = norms[R], fv = fixdot[R];
      float* orow = out0 + (size_t)R * OUT_DIM;
#pragma unroll
      for (int n = 0; n < 4; ++n) {
        int Cc = colb + n * 16 + rl;
        float val = acc[m][n][q];
        if (Cc == lab) {
          float c = fv / fmaxf(nv, EPSN);
          val = (c > 0.f) ? nv * (c * cm - sqrtf(fmaxf(1.f - c * c, 0.f)) * sm) : fv;
        }
        orow[Cc] = val;
      }
    }
  }
}

extern "C" void kernel_launch(void* const* d_in, const int* in_sizes, int n_in,
                              void* d_out, int out_size, void* d_ws, size_t ws_size,
                              hipStream_t stream) {
  const float* x = (const float*)d_in[0];
  const int* label = (const int*)d_in[1];
  const float* weight = (const float*)d_in[2];
  const float* mArr = (const float*)d_in[4];  // d_in[3] = s, unused by normfree output

  float* out0 = (float*)d_out;                               // [1024, 64000]
  float* wnOut = out0 + (size_t)B_ROWS * OUT_DIM;            // [64000, 512]

  char* ws = (char*)d_ws;
  float* norms = (float*)ws;                                 // 4 KiB
  float* fixdot = (float*)(ws + 4096);                       // 4 KiB
  unsigned short* xbf = (unsigned short*)(ws + 8192);        // 1 MiB

  prep_kernel<<<B_ROWS / 4, 256, 0, stream>>>(x, label, weight, norms, fixdot, xbf);
  gemm_fused_kernel<<<2000, 512, 0, stream>>>(weight, xbf, norms, fixdot, label,
                                              mArr, out0, wnOut);
}

// Round 9
// 244.559 us; speedup vs baseline: 1.1402x; 1.1402x over previous
//
#include <hip/hip_runtime.h>
#include <cstdint>

#define EPSN 1e-12f
static constexpr int B_ROWS = 1024;
static constexpr int IN_DIM = 512;
static constexpr int OUT_DIM = 64000;

typedef __attribute__((ext_vector_type(8))) short bf16x8;
typedef __attribute__((ext_vector_type(4))) float f32x4;

__device__ __forceinline__ unsigned short f2bf(float f) {
  uint32_t u = __builtin_bit_cast(uint32_t, f);
  u += 0x7fffu + ((u >> 16) & 1u);   // round-to-nearest-even
  return (unsigned short)(u >> 16);
}

__device__ __forceinline__ float wave_sum(float v) {
#pragma unroll
  for (int off = 32; off; off >>= 1) v += __shfl_xor(v, off);
  return v;
}

__device__ __forceinline__ void async16(const void* g, void* l) {
  __builtin_amdgcn_global_load_lds((const __attribute__((address_space(1))) uint32_t*)g,
                                   (__attribute__((address_space(3))) uint32_t*)l, 16, 0, 0);
}

// --- kernel 1: x-prep (norms + bf16 cast) + exact fixdot from RAW W ---
__global__ void prep_kernel(const float* __restrict__ X, const int* __restrict__ label,
                            const float* __restrict__ Wg, float* __restrict__ norms,
                            float* __restrict__ fixdot, unsigned short* __restrict__ xbf) {
  int lane = threadIdx.x & 63;
  int row = blockIdx.x * 4 + (threadIdx.x >> 6);
  const float* src = X + (size_t)row * IN_DIM + lane * 8;
  float4 a = *(const float4*)src;
  float4 b = *(const float4*)(src + 4);
  uint4 u;
  u.x = (uint32_t)f2bf(a.x) | ((uint32_t)f2bf(a.y) << 16);
  u.y = (uint32_t)f2bf(a.z) | ((uint32_t)f2bf(a.w) << 16);
  u.z = (uint32_t)f2bf(b.x) | ((uint32_t)f2bf(b.y) << 16);
  u.w = (uint32_t)f2bf(b.z) | ((uint32_t)f2bf(b.w) << 16);
  *(uint4*)(xbf + (size_t)row * IN_DIM + lane * 8) = u;
  float ssx = a.x * a.x;
  ssx = fmaf(a.y, a.y, ssx); ssx = fmaf(a.z, a.z, ssx); ssx = fmaf(a.w, a.w, ssx);
  ssx = fmaf(b.x, b.x, ssx); ssx = fmaf(b.y, b.y, ssx); ssx = fmaf(b.z, b.z, ssx);
  ssx = fmaf(b.w, b.w, ssx);
  int lab = label[row];
  const float* wsrc = Wg + (size_t)lab * IN_DIM + lane * 8;
  float4 wa = *(const float4*)wsrc, wb = *(const float4*)(wsrc + 4);
  float d = a.x * wa.x;
  d = fmaf(a.y, wa.y, d); d = fmaf(a.z, wa.z, d); d = fmaf(a.w, wa.w, d);
  d = fmaf(b.x, wb.x, d); d = fmaf(b.y, wb.y, d); d = fmaf(b.z, wb.z, d);
  d = fmaf(b.w, wb.w, d);
  float ssw = wa.x * wa.x;
  ssw = fmaf(wa.y, wa.y, ssw); ssw = fmaf(wa.z, wa.z, ssw); ssw = fmaf(wa.w, wa.w, ssw);
  ssw = fmaf(wb.x, wb.x, ssw); ssw = fmaf(wb.y, wb.y, ssw); ssw = fmaf(wb.z, wb.z, ssw);
  ssw = fmaf(wb.w, wb.w, ssw);
  ssx = wave_sum(ssx);
  d = wave_sum(d);
  ssw = wave_sum(ssw);
  if (lane == 0) {
    norms[row] = sqrtf(ssx);
    fixdot[row] = d / fmaxf(sqrtf(ssw), EPSN);   // = x . wn[lab], exact f32
  }
}

// --- kernel 2: FUSED normalize + bf16 MFMA GEMM + margin epilogue + wn write ---
// 256 thr / 4 waves (2Mx2N), BM=256 BN=128 BK=32, wave-tile 128x64 (acc[8][4],
// 32 MFMA/phase). LDS 64.5 KiB (A ring-3 48K + B ring-2 16K + invn) -> 2 blk/CU.
// A (xbf, L2-resident) via gload_lds, depth-2; B reg-staged from W f32 (loads
// issued one phase early, cvt+ds_write next phase). Verified mixed-queue vmcnt:
// per phase issue [B(sig+2)-loads x4, A(sig+2)-glds x4]; phase-sig wait
// vmcnt(4) leaves only A(sig+1): A(sig) (issued sig-2) is >=5 deep -> always
// drained; B-reg consumers are compiler-tracked. Prologue: row norms (4
// lanes/row), EXACT f32 wn write (quarter rows/block), then vmcnt(0) to empty
// the queue before the counted ring (stores must not pollute the count).
__global__ __launch_bounds__(256, 2) void gemm_fused_kernel(
    const float* __restrict__ Wg, const unsigned short* __restrict__ Abf,
    const float* __restrict__ norms, const float* __restrict__ fixdot,
    const int* __restrict__ label, const float* __restrict__ mArr,
    float* __restrict__ out0, float* __restrict__ wnOut) {
  __shared__ char smem[66048];  // B slots @0,8192; A slots @16384+s*16384 (3); invn @65536
  float* invnL = (float*)(smem + 65536);

  const int t = threadIdx.x;
  int flat = blockIdx.x;          // 2000 = 8 * 250, bijective XCD swizzle
  int xcd = flat & 7;
  int wk = (flat >> 3) + xcd * 250;
  int mT = wk & 3, nT = wk >> 2;  // 4 mT siblings per nT consecutive on one XCD
  int rowA0 = mT * 256, rowB0 = nT * 128;

  int lane = t & 63;
  int wid = t >> 6;
  int wm = wid >> 1, wn2 = wid & 1;   // 2M x 2N wave grid
  int rl = lane & 15, sl = lane >> 4;

  // ---- prologue A: B-panel row norms (4 threads/row, 2 passes) ----
#pragma unroll 1
  for (int pass = 0; pass < 2; ++pass) {
    int r = pass * 64 + (t >> 2);
    const float* src = Wg + (size_t)(rowB0 + r) * IN_DIM + (t & 3) * 128;
    float s = 0.f;
#pragma unroll
    for (int j = 0; j < 32; ++j) {
      float4 v = ((const float4*)src)[j];
      s = fmaf(v.x, v.x, s); s = fmaf(v.y, v.y, s);
      s = fmaf(v.z, v.z, s); s = fmaf(v.w, v.w, s);
    }
    s += __shfl_xor(s, 1);
    s += __shfl_xor(s, 2);
    if ((t & 3) == 0) invnL[r] = 1.0f / fmaxf(sqrtf(s), EPSN);
  }
  __syncthreads();

  // ---- prologue B: EXACT f32 wn write, quarter rows [mT*32, +32) ----
  {
    int r = mT * 32 + (t >> 3);
    float inv = invnL[r];
    const float* src = Wg + (size_t)(rowB0 + r) * IN_DIM + (t & 7) * 64;
    float* dst = wnOut + (size_t)(rowB0 + r) * IN_DIM + (t & 7) * 64;
#pragma unroll
    for (int j = 0; j < 16; ++j) {
      float4 v = ((const float4*)src)[j];
      v.x *= inv; v.y *= inv; v.z *= inv; v.w *= inv;
      ((float4*)dst)[j] = v;
    }
  }

  // ---- staging maps ----
  // B: 512 16B-chunks, 2/thread: chunk t -> (rB0, qB0), chunk t+256 -> (rB0+64, qB0)
  int rB0i = t >> 2, qB0i = t & 3;
  int rB1i = rB0i + 64;
  float invB0 = invnL[rB0i], invB1 = invnL[rB1i];
  const float* bW0 = Wg + (size_t)(rowB0 + rB0i) * IN_DIM + qB0i * 8;
  const float* bW1 = Wg + (size_t)(rowB0 + rB1i) * IN_DIM + qB0i * 8;
  int bOff0 = rB0i * 64 + ((qB0i ^ ((rB0i >> 1) & 3)) * 16);
  int bOff1 = rB1i * 64 + ((qB0i ^ ((rB1i >> 1) & 3)) * 16);

  // A: 1024 chunks, 4/thread, inverse-swizzled global source, linear LDS dest
  const unsigned short* aP[4];
#pragma unroll
  for (int c = 0; c < 4; ++c) {
    int ch = t + c * 256;
    int r = ch >> 2, q = (ch & 3) ^ ((r >> 1) & 3);
    aP[c] = Abf + (size_t)(rowA0 + r) * IN_DIM + q * 8;
  }

  auto issueA = [&](int sig) {
    char* aD = smem + 16384 + (sig % 3) * 16384;
    int kcol = sig * 32;
#pragma unroll
    for (int c = 0; c < 4; ++c) async16(aP[c] + kcol, aD + (t + c * 256) * 16);
  };

  float4 hB[4];
  auto loadB = [&](int sig) {
    int kcol = sig * 32;
    hB[0] = *(const float4*)(bW0 + kcol);
    hB[1] = *(const float4*)(bW0 + kcol + 4);
    hB[2] = *(const float4*)(bW1 + kcol);
    hB[3] = *(const float4*)(bW1 + kcol + 4);
  };
  auto writeB = [&](int sig, const float4* h) {
    char* bD = smem + (sig & 1) * 8192;
    uint4 u;
    u.x = (uint32_t)f2bf(h[0].x * invB0) | ((uint32_t)f2bf(h[0].y * invB0) << 16);
    u.y = (uint32_t)f2bf(h[0].z * invB0) | ((uint32_t)f2bf(h[0].w * invB0) << 16);
    u.z = (uint32_t)f2bf(h[1].x * invB0) | ((uint32_t)f2bf(h[1].y * invB0) << 16);
    u.w = (uint32_t)f2bf(h[1].z * invB0) | ((uint32_t)f2bf(h[1].w * invB0) << 16);
    *(uint4*)(bD + bOff0) = u;
    u.x = (uint32_t)f2bf(h[2].x * invB1) | ((uint32_t)f2bf(h[2].y * invB1) << 16);
    u.y = (uint32_t)f2bf(h[2].z * invB1) | ((uint32_t)f2bf(h[2].w * invB1) << 16);
    u.z = (uint32_t)f2bf(h[3].x * invB1) | ((uint32_t)f2bf(h[3].y * invB1) << 16);
    u.w = (uint32_t)f2bf(h[3].z * invB1) | ((uint32_t)f2bf(h[3].w * invB1) << 16);
    *(uint4*)(bD + bOff1) = u;
  };

  // ---- empty the VMEM queue (wn stores + norm loads), then counted prologue ----
  asm volatile("s_waitcnt vmcnt(0)" ::: "memory");
  float4 hB0[4];
  {
    hB0[0] = *(const float4*)(bW0);
    hB0[1] = *(const float4*)(bW0 + 4);
    hB0[2] = *(const float4*)(bW1);
    hB0[3] = *(const float4*)(bW1 + 4);
  }
  issueA(0);
  loadB(1);
  issueA(1);
  asm volatile("s_waitcnt vmcnt(12)" ::: "memory");  // B(0) regs ready
  writeB(0, hB0);

  f32x4 acc[8][4];
#pragma unroll
  for (int m = 0; m < 8; ++m)
#pragma unroll
    for (int n = 0; n < 4; ++n) acc[m][n] = (f32x4){0.f, 0.f, 0.f, 0.f};

#pragma unroll 1
  for (int sigma = 0; sigma < 16; ++sigma) {
    __builtin_amdgcn_sched_barrier(0);
    if (sigma <= 14) asm volatile("s_waitcnt vmcnt(4) lgkmcnt(0)" ::: "memory");
    else             asm volatile("s_waitcnt vmcnt(0) lgkmcnt(0)" ::: "memory");
    __builtin_amdgcn_s_barrier();
    __builtin_amdgcn_sched_barrier(0);

    if (sigma + 1 <= 15) writeB(sigma + 1, hB);   // regs arrived (ledger)
    if (sigma + 2 <= 15) { loadB(sigma + 2); issueA(sigma + 2); }

    const char* aB = smem + 16384 + (sigma % 3) * 16384;
    const char* bB = smem + (sigma & 1) * 8192;
    bf16x8 av[8], bv[4];
#pragma unroll
    for (int m = 0; m < 8; ++m) {
      int r = wm * 128 + m * 16 + rl;
      av[m] = *(const bf16x8*)(aB + r * 64 + ((sl ^ ((r >> 1) & 3)) * 16));
    }
#pragma unroll
    for (int n = 0; n < 4; ++n) {
      int r = wn2 * 64 + n * 16 + rl;
      bv[n] = *(const bf16x8*)(bB + r * 64 + ((sl ^ ((r >> 1) & 3)) * 16));
    }
    __builtin_amdgcn_s_setprio(1);
#pragma unroll
    for (int n = 0; n < 4; ++n)
#pragma unroll
      for (int m = 0; m < 8; ++m)
        acc[m][n] = __builtin_amdgcn_mfma_f32_16x16x32_bf16(av[m], bv[n], acc[m][n], 0, 0, 0);
    __builtin_amdgcn_s_setprio(0);
  }

  // ---- margin epilogue: out = rawdot except at (r, label[r]) ----
  float mm = mArr[0];
  float cm = cosf(mm), sm = sinf(mm);
  int rowb = rowA0 + wm * 128, colb = rowB0 + wn2 * 64;
#pragma unroll
  for (int m = 0; m < 8; ++m) {
#pragma unroll
    for (int q = 0; q < 4; ++q) {
      int R = rowb + m * 16 + sl * 4 + q;
      int lab = label[R];
      float nv = norms[R], fv = fixdot[R];
      float* orow = out0 + (size_t)R * OUT_DIM;
#pragma unroll
      for (int n = 0; n < 4; ++n) {
        int Cc = colb + n * 16 + rl;
        float val = acc[m][n][q];
        if (Cc == lab) {
          float c = fv / fmaxf(nv, EPSN);
          val = (c > 0.f) ? nv * (c * cm - sqrtf(fmaxf(1.f - c * c, 0.f)) * sm) : fv;
        }
        orow[Cc] = val;
      }
    }
  }
}

extern "C" void kernel_launch(void* const* d_in, const int* in_sizes, int n_in,
                              void* d_out, int out_size, void* d_ws, size_t ws_size,
                              hipStream_t stream) {
  const float* x = (const float*)d_in[0];
  const int* label = (const int*)d_in[1];
  const float* weight = (const float*)d_in[2];
  const float* mArr = (const float*)d_in[4];  // d_in[3] = s, unused by normfree output

  float* out0 = (float*)d_out;                               // [1024, 64000]
  float* wnOut = out0 + (size_t)B_ROWS * OUT_DIM;            // [64000, 512]

  char* ws = (char*)d_ws;
  float* norms = (float*)ws;                                 // 4 KiB
  float* fixdot = (float*)(ws + 4096);                       // 4 KiB
  unsigned short* xbf = (unsigned short*)(ws + 8192);        // 1 MiB

  prep_kernel<<<B_ROWS / 4, 256, 0, stream>>>(x, label, weight, norms, fixdot, xbf);
  gemm_fused_kernel<<<2000, 256, 0, stream>>>(weight, xbf, norms, fixdot, label,
                                              mArr, out0, wnOut);
}

// Round 10
// 210.321 us; speedup vs baseline: 1.3258x; 1.1628x over previous
//
#include <hip/hip_runtime.h>
#include <cstdint>

#define EPSN 1e-12f
static constexpr int B_ROWS = 1024;
static constexpr int IN_DIM = 512;
static constexpr int OUT_DIM = 64000;

typedef __attribute__((ext_vector_type(8))) short bf16x8;
typedef __attribute__((ext_vector_type(4))) float f32x4;

__device__ __forceinline__ unsigned short f2bf(float f) {
  uint32_t u = __builtin_bit_cast(uint32_t, f);
  u += 0x7fffu + ((u >> 16) & 1u);   // round-to-nearest-even
  return (unsigned short)(u >> 16);
}

__device__ __forceinline__ float bf2f(unsigned short h) {
  uint32_t u = (uint32_t)h << 16;
  return __builtin_bit_cast(float, u);
}

__device__ __forceinline__ float wave_sum(float v) {
#pragma unroll
  for (int off = 32; off; off >>= 1) v += __shfl_xor(v, off);
  return v;
}

__device__ __forceinline__ void async16(const void* g, void* l) {
  __builtin_amdgcn_global_load_lds((const __attribute__((address_space(1))) uint32_t*)g,
                                   (__attribute__((address_space(3))) uint32_t*)l, 16, 0, 0);
}

// --- kernel 1: x-prep (norms + bf16 cast) + exact fixdot from RAW W ---
__global__ void prep_kernel(const float* __restrict__ X, const int* __restrict__ label,
                            const float* __restrict__ Wg, float* __restrict__ norms,
                            float* __restrict__ fixdot, unsigned short* __restrict__ xbf) {
  int lane = threadIdx.x & 63;
  int row = blockIdx.x * 4 + (threadIdx.x >> 6);
  const float* src = X + (size_t)row * IN_DIM + lane * 8;
  float4 a = *(const float4*)src;
  float4 b = *(const float4*)(src + 4);
  uint4 u;
  u.x = (uint32_t)f2bf(a.x) | ((uint32_t)f2bf(a.y) << 16);
  u.y = (uint32_t)f2bf(a.z) | ((uint32_t)f2bf(a.w) << 16);
  u.z = (uint32_t)f2bf(b.x) | ((uint32_t)f2bf(b.y) << 16);
  u.w = (uint32_t)f2bf(b.z) | ((uint32_t)f2bf(b.w) << 16);
  *(uint4*)(xbf + (size_t)row * IN_DIM + lane * 8) = u;
  float ssx = a.x * a.x;
  ssx = fmaf(a.y, a.y, ssx); ssx = fmaf(a.z, a.z, ssx); ssx = fmaf(a.w, a.w, ssx);
  ssx = fmaf(b.x, b.x, ssx); ssx = fmaf(b.y, b.y, ssx); ssx = fmaf(b.z, b.z, ssx);
  ssx = fmaf(b.w, b.w, ssx);
  int lab = label[row];
  const float* wsrc = Wg + (size_t)lab * IN_DIM + lane * 8;
  float4 wa = *(const float4*)wsrc, wb = *(const float4*)(wsrc + 4);
  float d = a.x * wa.x;
  d = fmaf(a.y, wa.y, d); d = fmaf(a.z, wa.z, d); d = fmaf(a.w, wa.w, d);
  d = fmaf(b.x, wb.x, d); d = fmaf(b.y, wb.y, d); d = fmaf(b.z, wb.z, d);
  d = fmaf(b.w, wb.w, d);
  float ssw = wa.x * wa.x;
  ssw = fmaf(wa.y, wa.y, ssw); ssw = fmaf(wa.z, wa.z, ssw); ssw = fmaf(wa.w, wa.w, ssw);
  ssw = fmaf(wb.x, wb.x, ssw); ssw = fmaf(wb.y, wb.y, ssw); ssw = fmaf(wb.z, wb.z, ssw);
  ssw = fmaf(wb.w, wb.w, ssw);
  ssx = wave_sum(ssx);
  d = wave_sum(d);
  ssw = wave_sum(ssw);
  if (lane == 0) {
    norms[row] = sqrtf(ssx);
    fixdot[row] = d / fmaxf(sqrtf(ssw), EPSN);   // = x . wn[lab], exact f32
  }
}

// --- kernel 2: W -> normalized bf16 (wbf); wn f32 written by GEMM epilogue ---
__global__ void wcast_kernel(const float* __restrict__ Wg, unsigned short* __restrict__ wbf) {
  int lane = threadIdx.x & 63;
  int row = blockIdx.x * 4 + (threadIdx.x >> 6);
  const float* src = Wg + (size_t)row * IN_DIM + lane * 8;
  float4 a = *(const float4*)src;
  float4 b = *(const float4*)(src + 4);
  float ss = a.x * a.x;
  ss = fmaf(a.y, a.y, ss); ss = fmaf(a.z, a.z, ss); ss = fmaf(a.w, a.w, ss);
  ss = fmaf(b.x, b.x, ss); ss = fmaf(b.y, b.y, ss); ss = fmaf(b.z, b.z, ss);
  ss = fmaf(b.w, b.w, ss);
  ss = wave_sum(ss);
  float inv = 1.0f / fmaxf(sqrtf(ss), EPSN);
  uint4 u;
  u.x = (uint32_t)f2bf(a.x * inv) | ((uint32_t)f2bf(a.y * inv) << 16);
  u.y = (uint32_t)f2bf(a.z * inv) | ((uint32_t)f2bf(a.w * inv) << 16);
  u.z = (uint32_t)f2bf(b.x * inv) | ((uint32_t)f2bf(b.y * inv) << 16);
  u.w = (uint32_t)f2bf(b.z * inv) | ((uint32_t)f2bf(b.w * inv) << 16);
  *(uint4*)(wbf + (size_t)row * IN_DIM + lane * 8) = u;
}

// --- kernel 3: bf16 MFMA GEMM (M=1024,N=64000,K=512) + margin epilogue + wn write ---
// R3 skeleton (proven no-spill): 512 thr / 8 waves (2Mx4N), BM=BN=256, BK=32,
// wave-tile 128x64 (acc[8][4], 32 MFMA/phase). RING-2 LDS = 64 KiB -> 2 blocks/CU:
// one block's bursty 256 KB epilogue overlaps the other's K-loop (the R3 limiter).
// Ledger: prologue subs 0,1; phase sig: vmcnt(4) [sub sig+1 in flight] ->
// barrier -> 12 ds_read + 32 MFMA (reads drained via MFMA reg-deps) ->
// end barrier -> issue sub sig+2 into slot sig&1 (readers provably done).
__global__ __launch_bounds__(512, 2) void gemm_epi_kernel(
    const unsigned short* __restrict__ Abf, const unsigned short* __restrict__ Bbf,
    const float* __restrict__ norms, const float* __restrict__ fixdot,
    const int* __restrict__ label, const float* __restrict__ mArr,
    float* __restrict__ out0, float* __restrict__ wnOut) {
  __shared__ char smem[65536];  // A slots @0,16384; B slots @32768,49152

  const int t = threadIdx.x;
  int flat = blockIdx.x;          // 1000 = 8 * 125, bijective XCD swizzle
  int xcd = flat & 7;
  int wk = (flat >> 3) + xcd * 125;
  int mT = wk & 3, nT = wk >> 2;  // 4 mT siblings per nT consecutive on one XCD
  int rowA0 = mT * 256, rowB0 = nT * 256;

  int lane = t & 63;
  int wid = t >> 6;
  int wm = wid >> 2, wn2 = wid & 3;   // 2M x 4N wave grid
  int rl = lane & 15, sl = lane >> 4;

  // staging chunk map (inverse swizzle): chunk c -> row r = c>>2, 16B-slot q
  int r0 = t >> 2, q0 = (t & 3) ^ ((r0 >> 1) & 3);
  int r1 = (t + 512) >> 2, q1 = ((t + 512) & 3) ^ ((r1 >> 1) & 3);
  const unsigned short* aP0 = Abf + (size_t)(rowA0 + r0) * IN_DIM + q0 * 8;
  const unsigned short* aP1 = Abf + (size_t)(rowA0 + r1) * IN_DIM + q1 * 8;
  const unsigned short* bP0 = Bbf + (size_t)(rowB0 + r0) * IN_DIM + q0 * 8;
  const unsigned short* bP1 = Bbf + (size_t)(rowB0 + r1) * IN_DIM + q1 * 8;

  auto issueSub = [&](int sig) {
    int kcol = sig * 32;
    char* aD = smem + (sig & 1) * 16384;
    char* bD = smem + 32768 + (sig & 1) * 16384;
    async16(aP0 + kcol, aD + t * 16);
    async16(aP1 + kcol, aD + (t + 512) * 16);
    async16(bP0 + kcol, bD + t * 16);
    async16(bP1 + kcol, bD + (t + 512) * 16);
  };

  issueSub(0); issueSub(1);   // ring-2 prologue (8 gloads/thread)

  f32x4 acc[8][4];
#pragma unroll
  for (int m = 0; m < 8; ++m)
#pragma unroll
    for (int n = 0; n < 4; ++n) acc[m][n] = (f32x4){0.f, 0.f, 0.f, 0.f};

#pragma unroll 1
  for (int sigma = 0; sigma < 16; ++sigma) {
    __builtin_amdgcn_sched_barrier(0);
    if (sigma <= 14) asm volatile("s_waitcnt vmcnt(4)" ::: "memory");
    else             asm volatile("s_waitcnt vmcnt(0)" ::: "memory");
    __builtin_amdgcn_s_barrier();
    __builtin_amdgcn_sched_barrier(0);

    const char* aB = smem + (sigma & 1) * 16384;
    const char* bB = smem + 32768 + (sigma & 1) * 16384;
    bf16x8 av[8], bv[4];
#pragma unroll
    for (int m = 0; m < 8; ++m) {
      int r = wm * 128 + m * 16 + rl;
      av[m] = *(const bf16x8*)(aB + r * 64 + ((sl ^ ((r >> 1) & 3)) * 16));
    }
#pragma unroll
    for (int n = 0; n < 4; ++n) {
      int r = wn2 * 64 + n * 16 + rl;
      bv[n] = *(const bf16x8*)(bB + r * 64 + ((sl ^ ((r >> 1) & 3)) * 16));
    }
    __builtin_amdgcn_s_setprio(1);
#pragma unroll
    for (int n = 0; n < 4; ++n)
#pragma unroll
      for (int m = 0; m < 8; ++m)
        acc[m][n] = __builtin_amdgcn_mfma_f32_16x16x32_bf16(av[m], bv[n], acc[m][n], 0, 0, 0);
    __builtin_amdgcn_s_setprio(0);
    __builtin_amdgcn_s_barrier();          // all waves done reading slot sigma&1
    __builtin_amdgcn_sched_barrier(0);
    if (sigma + 2 <= 15) issueSub(sigma + 2);   // reuse slot sigma&1 safely
  }

  // ---- wn f32 output: this mT-sibling writes 64 rows of panel nT from L2-hot
  // wbf (bf16-rounded; error << threshold, proven R5-R7). ----
  {
    int r = t >> 3;                      // 0..63
    int c0 = (t & 7) * 64;               // 64 floats per thread
    int row = rowB0 + mT * 64 + r;
    const unsigned short* srcp = Bbf + (size_t)row * IN_DIM + c0;
    float* dst = wnOut + (size_t)row * IN_DIM + c0;
#pragma unroll
    for (int g = 0; g < 8; ++g) {
      uint4 uu = *(const uint4*)(srcp + g * 8);
      float4 f;
      f.x = bf2f((unsigned short)(uu.x & 0xffff)); f.y = bf2f((unsigned short)(uu.x >> 16));
      f.z = bf2f((unsigned short)(uu.y & 0xffff)); f.w = bf2f((unsigned short)(uu.y >> 16));
      *(float4*)(dst + g * 8) = f;
      f.x = bf2f((unsigned short)(uu.z & 0xffff)); f.y = bf2f((unsigned short)(uu.z >> 16));
      f.z = bf2f((unsigned short)(uu.w & 0xffff)); f.w = bf2f((unsigned short)(uu.w >> 16));
      *(float4*)(dst + g * 8 + 4) = f;
    }
  }

  // ---- margin epilogue: out = rawdot except at (r, label[r]) ----
  float mm = mArr[0];
  float cm = cosf(mm), sm = sinf(mm);
  int rowb = rowA0 + wm * 128, colb = rowB0 + wn2 * 64;
#pragma unroll
  for (int m = 0; m < 8; ++m) {
#pragma unroll
    for (int q = 0; q < 4; ++q) {
      int R = rowb + m * 16 + sl * 4 + q;
      int lab = label[R];
      float nv = norms[R], fv = fixdot[R];
      float* orow = out0 + (size_t)R * OUT_DIM;
#pragma unroll
      for (int n = 0; n < 4; ++n) {
        int Cc = colb + n * 16 + rl;
        float val = acc[m][n][q];
        if (Cc == lab) {
          float c = fv / fmaxf(nv, EPSN);
          val = (c > 0.f) ? nv * (c * cm - sqrtf(fmaxf(1.f - c * c, 0.f)) * sm) : fv;
        }
        orow[Cc] = val;
      }
    }
  }
}

extern "C" void kernel_launch(void* const* d_in, const int* in_sizes, int n_in,
                              void* d_out, int out_size, void* d_ws, size_t ws_size,
                              hipStream_t stream) {
  const float* x = (const float*)d_in[0];
  const int* label = (const int*)d_in[1];
  const float* weight = (const float*)d_in[2];
  const float* mArr = (const float*)d_in[4];  // d_in[3] = s, unused by normfree output

  float* out0 = (float*)d_out;                               // [1024, 64000]
  float* wnOut = out0 + (size_t)B_ROWS * OUT_DIM;            // [64000, 512]

  char* ws = (char*)d_ws;
  float* norms = (float*)ws;                                 // 4 KiB
  float* fixdot = (float*)(ws + 4096);                       // 4 KiB
  unsigned short* xbf = (unsigned short*)(ws + 8192);        // 1 MiB
  unsigned short* wbf = (unsigned short*)(ws + 8192 + 2ull * B_ROWS * IN_DIM);  // 65.5 MiB

  prep_kernel<<<B_ROWS / 4, 256, 0, stream>>>(x, label, weight, norms, fixdot, xbf);
  wcast_kernel<<<OUT_DIM / 4, 256, 0, stream>>>(weight, wbf);
  gemm_epi_kernel<<<1000, 512, 0, stream>>>(xbf, wbf, norms, fixdot, label, mArr,
                                            out0, wnOut);
}

// Round 11
// 209.535 us; speedup vs baseline: 1.3308x; 1.0038x over previous
//
#include <hip/hip_runtime.h>
#include <cstdint>

#define EPSN 1e-12f
static constexpr int B_ROWS = 1024;
static constexpr int IN_DIM = 512;
static constexpr int OUT_DIM = 64000;

typedef __attribute__((ext_vector_type(8))) short bf16x8;
typedef __attribute__((ext_vector_type(4))) float f32x4;

__device__ __forceinline__ unsigned short f2bf(float f) {
  uint32_t u = __builtin_bit_cast(uint32_t, f);
  u += 0x7fffu + ((u >> 16) & 1u);   // round-to-nearest-even
  return (unsigned short)(u >> 16);
}

__device__ __forceinline__ float bf2f(unsigned short h) {
  uint32_t u = (uint32_t)h << 16;
  return __builtin_bit_cast(float, u);
}

__device__ __forceinline__ float wave_sum(float v) {
#pragma unroll
  for (int off = 32; off; off >>= 1) v += __shfl_xor(v, off);
  return v;
}

__device__ __forceinline__ void async16(const void* g, void* l) {
  __builtin_amdgcn_global_load_lds((const __attribute__((address_space(1))) uint32_t*)g,
                                   (__attribute__((address_space(3))) uint32_t*)l, 16, 0, 0);
}

// --- kernel 1: MERGED wcast (W -> normalized bf16) + x-prep (norms/xbf/fixdot) ---
// blocks [0,16000): wcast 4 W-rows each; blocks [16000,16256): prep 4 x-rows each.
__global__ void prep_wcast_kernel(const float* __restrict__ Wg, const float* __restrict__ X,
                                  const int* __restrict__ label,
                                  unsigned short* __restrict__ wbf,
                                  float* __restrict__ norms, float* __restrict__ fixdot,
                                  unsigned short* __restrict__ xbf) {
  int lane = threadIdx.x & 63;
  if (blockIdx.x < 16000) {
    int row = blockIdx.x * 4 + (threadIdx.x >> 6);
    const float* src = Wg + (size_t)row * IN_DIM + lane * 8;
    float4 a = *(const float4*)src;
    float4 b = *(const float4*)(src + 4);
    float ss = a.x * a.x;
    ss = fmaf(a.y, a.y, ss); ss = fmaf(a.z, a.z, ss); ss = fmaf(a.w, a.w, ss);
    ss = fmaf(b.x, b.x, ss); ss = fmaf(b.y, b.y, ss); ss = fmaf(b.z, b.z, ss);
    ss = fmaf(b.w, b.w, ss);
    ss = wave_sum(ss);
    float inv = 1.0f / fmaxf(sqrtf(ss), EPSN);
    uint4 u;
    u.x = (uint32_t)f2bf(a.x * inv) | ((uint32_t)f2bf(a.y * inv) << 16);
    u.y = (uint32_t)f2bf(a.z * inv) | ((uint32_t)f2bf(a.w * inv) << 16);
    u.z = (uint32_t)f2bf(b.x * inv) | ((uint32_t)f2bf(b.y * inv) << 16);
    u.w = (uint32_t)f2bf(b.z * inv) | ((uint32_t)f2bf(b.w * inv) << 16);
    *(uint4*)(wbf + (size_t)row * IN_DIM + lane * 8) = u;
  } else {
    int row = (blockIdx.x - 16000) * 4 + (threadIdx.x >> 6);
    const float* src = X + (size_t)row * IN_DIM + lane * 8;
    float4 a = *(const float4*)src;
    float4 b = *(const float4*)(src + 4);
    uint4 u;
    u.x = (uint32_t)f2bf(a.x) | ((uint32_t)f2bf(a.y) << 16);
    u.y = (uint32_t)f2bf(a.z) | ((uint32_t)f2bf(a.w) << 16);
    u.z = (uint32_t)f2bf(b.x) | ((uint32_t)f2bf(b.y) << 16);
    u.w = (uint32_t)f2bf(b.z) | ((uint32_t)f2bf(b.w) << 16);
    *(uint4*)(xbf + (size_t)row * IN_DIM + lane * 8) = u;
    float ssx = a.x * a.x;
    ssx = fmaf(a.y, a.y, ssx); ssx = fmaf(a.z, a.z, ssx); ssx = fmaf(a.w, a.w, ssx);
    ssx = fmaf(b.x, b.x, ssx); ssx = fmaf(b.y, b.y, ssx); ssx = fmaf(b.z, b.z, ssx);
    ssx = fmaf(b.w, b.w, ssx);
    int lab = label[row];
    const float* wsrc = Wg + (size_t)lab * IN_DIM + lane * 8;
    float4 wa = *(const float4*)wsrc, wb = *(const float4*)(wsrc + 4);
    float d = a.x * wa.x;
    d = fmaf(a.y, wa.y, d); d = fmaf(a.z, wa.z, d); d = fmaf(a.w, wa.w, d);
    d = fmaf(b.x, wb.x, d); d = fmaf(b.y, wb.y, d); d = fmaf(b.z, wb.z, d);
    d = fmaf(b.w, wb.w, d);
    float ssw = wa.x * wa.x;
    ssw = fmaf(wa.y, wa.y, ssw); ssw = fmaf(wa.z, wa.z, ssw); ssw = fmaf(wa.w, wa.w, ssw);
    ssw = fmaf(wb.x, wb.x, ssw); ssw = fmaf(wb.y, wb.y, ssw); ssw = fmaf(wb.z, wb.z, ssw);
    ssw = fmaf(wb.w, wb.w, ssw);
    ssx = wave_sum(ssx);
    d = wave_sum(d);
    ssw = wave_sum(ssw);
    if (lane == 0) {
      norms[row] = sqrtf(ssx);
      fixdot[row] = d / fmaxf(sqrtf(ssw), EPSN);   // = x . wn[lab], exact f32
    }
  }
}

// --- kernel 2: bf16 MFMA GEMM + margin epilogue + wn write ---
// BM=256 BN=128 BK=32; 512 thr / 8 waves (4Mx2N), wave-tile 64x64: acc[4][4]
// = 64 VGPR -> total ~120 <= 128 cap (__launch_bounds__(512,4)) -> TWO blocks
// per CU (the R3-plateau fix: one block's bursty epilogue overlaps the other's
// K-loop). Ring-3 LDS 72 KiB (x2 = 144 <= 160). Single barrier per phase
// (R6-verified): {vmcnt(3|0) -> barrier -> issue sub sig+2 into slot (sig-1)%3
// (its readers all passed this barrier) -> 8 ds_read -> 16 MFMA}.
// OPERAND-SWAPPED MFMA: acc = mfma(bv, av, acc) -> lane holds 4 CONSECUTIVE
// COLUMNS of one row -> float4 C-stores (4x fewer store insts than scalar).
__global__ __launch_bounds__(512, 4) void gemm_epi_kernel(
    const unsigned short* __restrict__ Abf, const unsigned short* __restrict__ Bbf,
    const float* __restrict__ norms, const float* __restrict__ fixdot,
    const int* __restrict__ label, const float* __restrict__ mArr,
    float* __restrict__ out0, float* __restrict__ wnOut) {
  __shared__ char smem[73728];   // slot s @ s*24576: A 16K, B 8K @ +16384

  const int t = threadIdx.x;
  int flat = blockIdx.x;          // 2000 = 8 * 250, bijective XCD swizzle
  int xcd = flat & 7;
  int wk = (flat >> 3) + xcd * 250;
  int mT = wk & 3, nT = wk >> 2;  // 4 mT siblings per nT consecutive on one XCD
  int rowA0 = mT * 256, rowB0 = nT * 128;

  int lane = t & 63;
  int wid = t >> 6;
  int wm = wid >> 1, wn2 = wid & 1;   // 4M x 2N wave grid
  int rl = lane & 15, sl = lane >> 4;

  // staging chunk map (inverse swizzle): chunk c -> row r = c>>2, 16B-slot q
  int rA0 = t >> 2, qA0 = (t & 3) ^ ((rA0 >> 1) & 3);
  int rA1 = (t + 512) >> 2, qA1 = ((t + 512) & 3) ^ ((rA1 >> 1) & 3);
  int rB = t >> 2, qB = (t & 3) ^ ((rB >> 1) & 3);
  const unsigned short* aP0 = Abf + (size_t)(rowA0 + rA0) * IN_DIM + qA0 * 8;
  const unsigned short* aP1 = Abf + (size_t)(rowA0 + rA1) * IN_DIM + qA1 * 8;
  const unsigned short* bP0 = Bbf + (size_t)(rowB0 + rB) * IN_DIM + qB * 8;

  auto issueSub = [&](int sig, int slot) {
    int kcol = sig * 32;
    char* aD = smem + slot * 24576;
    async16(aP0 + kcol, aD + t * 16);
    async16(aP1 + kcol, aD + (t + 512) * 16);
    async16(bP0 + kcol, aD + 16384 + t * 16);
  };

  issueSub(0, 0); issueSub(1, 1);   // depth-2 prologue (6 gloads/thread)

  f32x4 acc[4][4];
#pragma unroll
  for (int m = 0; m < 4; ++m)
#pragma unroll
    for (int n = 0; n < 4; ++n) acc[m][n] = (f32x4){0.f, 0.f, 0.f, 0.f};

  int slotR = 0, slotW = 2;
#pragma unroll 1
  for (int sigma = 0; sigma < 16; ++sigma) {
    __builtin_amdgcn_sched_barrier(0);
    if (sigma <= 14) asm volatile("s_waitcnt vmcnt(3)" ::: "memory");
    else             asm volatile("s_waitcnt vmcnt(0)" ::: "memory");
    __builtin_amdgcn_s_barrier();
    __builtin_amdgcn_sched_barrier(0);
    if (sigma + 2 <= 15) issueSub(sigma + 2, slotW);  // slot (sigma-1)%3: safe

    const char* aB = smem + slotR * 24576;
    const char* bB = aB + 16384;
    bf16x8 av[4], bv[4];
#pragma unroll
    for (int m = 0; m < 4; ++m) {
      int r = wm * 64 + m * 16 + rl;
      av[m] = *(const bf16x8*)(aB + r * 64 + ((sl ^ ((r >> 1) & 3)) * 16));
    }
#pragma unroll
    for (int n = 0; n < 4; ++n) {
      int r = wn2 * 64 + n * 16 + rl;
      bv[n] = *(const bf16x8*)(bB + r * 64 + ((sl ^ ((r >> 1) & 3)) * 16));
    }
    __builtin_amdgcn_s_setprio(1);
#pragma unroll
    for (int n = 0; n < 4; ++n)
#pragma unroll
      for (int m = 0; m < 4; ++m)   // SWAPPED: D^T layout -> row-contig lanes
        acc[m][n] = __builtin_amdgcn_mfma_f32_16x16x32_bf16(bv[n], av[m], acc[m][n], 0, 0, 0);
    __builtin_amdgcn_s_setprio(0);
    slotR = (slotR == 2) ? 0 : slotR + 1;
    slotW = (slotW == 2) ? 0 : slotW + 1;
  }

  // ---- margin epilogue: float4 stores; lane holds out[R][cbase..cbase+3] ----
  float mm = mArr[0];
  float cm = cosf(mm), sm = sinf(mm);
  int rowb = rowA0 + wm * 64, colb = rowB0 + wn2 * 64;
#pragma unroll
  for (int m = 0; m < 4; ++m) {
    int R = rowb + m * 16 + rl;
    int lab = label[R];
    float nv = norms[R], fv = fixdot[R];
    float* orow = out0 + (size_t)R * OUT_DIM;
#pragma unroll
    for (int n = 0; n < 4; ++n) {
      int cbase = colb + n * 16 + sl * 4;
      f32x4 v = acc[m][n];
      if ((unsigned)(lab - cbase) < 4u) {
        float c = fv / fmaxf(nv, EPSN);
        float val = (c > 0.f) ? nv * (c * cm - sqrtf(fmaxf(1.f - c * c, 0.f)) * sm) : fv;
        v[lab - cbase] = val;
      }
      *(f32x4*)(orow + cbase) = v;
    }
  }

  // ---- wn f32 output: this mT-sibling writes 32 rows of panel nT from L2-hot
  // wbf (bf16-rounded; error << threshold, proven R5-R10). ----
  {
    int r = t >> 4;                      // 0..31
    int c0 = (t & 15) * 32;              // 32 floats per thread
    int row = rowB0 + mT * 32 + r;
    const unsigned short* srcp = Bbf + (size_t)row * IN_DIM + c0;
    float* dst = wnOut + (size_t)row * IN_DIM + c0;
#pragma unroll
    for (int g = 0; g < 4; ++g) {
      uint4 uu = *(const uint4*)(srcp + g * 8);
      float4 f;
      f.x = bf2f((unsigned short)(uu.x & 0xffff)); f.y = bf2f((unsigned short)(uu.x >> 16));
      f.z = bf2f((unsigned short)(uu.y & 0xffff)); f.w = bf2f((unsigned short)(uu.y >> 16));
      *(float4*)(dst + g * 8) = f;
      f.x = bf2f((unsigned short)(uu.z & 0xffff)); f.y = bf2f((unsigned short)(uu.z >> 16));
      f.z = bf2f((unsigned short)(uu.w & 0xffff)); f.w = bf2f((unsigned short)(uu.w >> 16));
      *(float4*)(dst + g * 8 + 4) = f;
    }
  }
}

extern "C" void kernel_launch(void* const* d_in, const int* in_sizes, int n_in,
                              void* d_out, int out_size, void* d_ws, size_t ws_size,
                              hipStream_t stream) {
  const float* x = (const float*)d_in[0];
  const int* label = (const int*)d_in[1];
  const float* weight = (const float*)d_in[2];
  const float* mArr = (const float*)d_in[4];  // d_in[3] = s, unused by normfree output

  float* out0 = (float*)d_out;                               // [1024, 64000]
  float* wnOut = out0 + (size_t)B_ROWS * OUT_DIM;            // [64000, 512]

  char* ws = (char*)d_ws;
  float* norms = (float*)ws;                                 // 4 KiB
  float* fixdot = (float*)(ws + 4096);                       // 4 KiB
  unsigned short* xbf = (unsigned short*)(ws + 8192);        // 1 MiB
  unsigned short* wbf = (unsigned short*)(ws + 8192 + 2ull * B_ROWS * IN_DIM);  // 65.5 MiB

  prep_wcast_kernel<<<16256, 256, 0, stream>>>(weight, x, label, wbf, norms, fixdot, xbf);
  gemm_epi_kernel<<<2000, 512, 0, stream>>>(xbf, wbf, norms, fixdot, label, mArr,
                                            out0, wnOut);
}